// Round 13
// baseline (325.807 us; speedup 1.0000x reference)
//
#include <hip/hip_runtime.h>
#include <stddef.h>
#include <stdint.h>

// ---------- problem dims (fixed by setup_inputs) ----------
#define BDIM 2
#define SDIM 2048
#define DDIM 1024
#define FDIM 4096
#define ENUM 8
#define KSEL 2
#define TTOK (BDIM * SDIM)        // 4096 tokens
#define PPAIR (TTOK * KSEL)       // 8192 (token,k) pairs
#define VOUT ((size_t)TTOK * DDIM) // 4194304 floats of "mixed"

typedef float f32x4 __attribute__((ext_vector_type(4)));
typedef short bf16x8 __attribute__((ext_vector_type(8)));
typedef unsigned short u16x8 __attribute__((ext_vector_type(8)));
typedef unsigned short u16x4 __attribute__((ext_vector_type(4)));

#define WAITV(N) asm volatile("s_waitcnt vmcnt(" #N ")" ::: "memory")
#define BARX() asm volatile("s_barrier" ::: "memory")

__device__ __forceinline__ unsigned short f2bf(float f) {
  unsigned int u = __float_as_uint(f);
  u += 0x7fffu + ((u >> 16) & 1u);   // RNE
  return (unsigned short)(u >> 16);
}

__device__ __forceinline__ float gelu_tanh(float x) {
  float u = 0.7978845608028654f * (x + 0.044715f * x * x * x);
  float e = __expf(2.0f * u);
  float t = 1.0f - 2.0f / (e + 1.0f);   // tanh(u), safe at +-inf
  return 0.5f * x * (1.0f + t);
}

__device__ __forceinline__ void gload16(const void* g, void* l) {
  __builtin_amdgcn_global_load_lds(
      (const __attribute__((address_space(1))) unsigned int*)g,
      (__attribute__((address_space(3))) unsigned int*)l, 16, 0, 0);
}

// ---------- fused pre: cvt_hidden (b<2048) + statsA (2048..2063) + routing (2064) ----------
__global__ __launch_bounds__(256) void pre_kernel(const float* __restrict__ hidden,
                                                  unsigned short* __restrict__ hB,
                                                  const float* __restrict__ lg,
                                                  float* __restrict__ pst,
                                                  const int* __restrict__ eidx,
                                                  int* __restrict__ g_cnt,
                                                  int* __restrict__ g_off,
                                                  int* __restrict__ pairTok,
                                                  int* __restrict__ inv,
                                                  int* __restrict__ b256E,
                                                  int* __restrict__ b256M,
                                                  int* __restrict__ b128E,
                                                  int* __restrict__ b128M,
                                                  int* __restrict__ nT) {
  const int b = blockIdx.x;
  const int tid = threadIdx.x;
  if (b < 2048) {
    // hidden fp32 -> bf16 (8 elems/thread)
    const int i = b * 256 + tid;
    f32x4 a = ((const f32x4*)hidden)[(size_t)i * 2];
    f32x4 c = ((const f32x4*)hidden)[(size_t)i * 2 + 1];
    u16x8 o;
    o[0] = f2bf(a[0]); o[1] = f2bf(a[1]); o[2] = f2bf(a[2]); o[3] = f2bf(a[3]);
    o[4] = f2bf(c[0]); o[5] = f2bf(c[1]); o[6] = f2bf(c[2]); o[7] = f2bf(c[3]);
    ((u16x8*)hB)[i] = o;
    return;
  }
  if (b < 2064) {
    // statsA
    __shared__ float se[256], sm[256];
    const int r = (b - 2048) * 256 + tid;
    float v[ENUM];
    float mx = -1e30f;
#pragma unroll
    for (int i = 0; i < ENUM; ++i) { v[i] = lg[r * ENUM + i]; mx = fmaxf(mx, v[i]); }
    float s = 0.f;
#pragma unroll
    for (int i = 0; i < ENUM; ++i) { v[i] = __expf(v[i] - mx); s += v[i]; }
    float invs = 1.f / s;
    float p1 = -1.f, p2 = -1.f, e_ = 0.f;
#pragma unroll
    for (int i = 0; i < ENUM; ++i) {
      float p = v[i] * invs;
      e_ -= p * logf(fmaxf(p, 1e-9f));
      if (p > p1) { p2 = p1; p1 = p; } else if (p > p2) { p2 = p; }
    }
    se[tid] = e_; sm[tid] = p1 - p2;
    __syncthreads();
    for (int st = 128; st > 0; st >>= 1) {
      if (tid < (unsigned)st) { se[tid] += se[tid + st]; sm[tid] += sm[tid + st]; }
      __syncthreads();
    }
    if (tid == 0) { pst[(b - 2048) * 2] = se[0]; pst[(b - 2048) * 2 + 1] = sm[0]; }
    return;
  }
  // routing (single block)
  __shared__ int sc[ENUM], so[ENUM], scur[ENUM];
  if (tid < ENUM) sc[tid] = 0;
  __syncthreads();
  for (int p = tid; p < PPAIR; p += 256) atomicAdd(&sc[eidx[p]], 1);
  __syncthreads();
  if (tid == 0) {
    int o = 0, n256 = 0, n128 = 0;
    for (int e = 0; e < ENUM; ++e) {
      so[e] = o;
      const int cnt = sc[e];
      const int nf = cnt >> 8;              // full 256-row blocks
      const int rem = cnt - (nf << 8);
      for (int i = 0; i < nf; ++i) { b256E[n256] = e; b256M[n256] = i << 8; ++n256; }
      const int np = (rem + 127) >> 7;      // 0..2 partial 128-row blocks
      for (int j = 0; j < np; ++j) { b128E[n128] = e; b128M[n128] = (nf << 8) + (j << 7); ++n128; }
      o += cnt;
    }
    nT[0] = n256; nT[1] = n128;             // n256 <= 32, n128 <= 16
  }
  __syncthreads();
  if (tid < ENUM) { scur[tid] = so[tid]; g_cnt[tid] = sc[tid]; g_off[tid] = so[tid]; }
  __syncthreads();
  for (int p = tid; p < PPAIR; p += 256) {
    int e = eidx[p];
    int pos = atomicAdd(&scur[e], 1);
    pairTok[pos] = p >> 1;  // token id
    inv[p] = pos;           // grouped position of pair p
  }
}

// ---------- router stats, stage B ----------
__global__ void statsB_kernel(const float* __restrict__ pst, float* __restrict__ out) {
  if (threadIdx.x == 0) {
    float a = 0.f, b = 0.f;
    for (int i = 0; i < 16; ++i) { a += pst[2 * i]; b += pst[2 * i + 1]; }
    out[VOUT]     = a / (float)TTOK;
    out[VOUT + 1] = b / (float)TTOK;
  }
}

// ---------- merged transpose+convert, 64x64 tiles, FULL-LINE WRITES ----------
// z<8 -> w1 [1024][4096]; z>=8 -> w2 [4096][1024]
// reads: 256B row segments (f32x4/lane); writes: one 128B segment per output row
// (8 lanes x u16x8 = full 64-elem bf16 row span of the tile in one issue)
// LDS pitch 65: gather banks {c,c+8,c+16,c+24}x2 = 2-way (free, m136)
__global__ __launch_bounds__(256) void transpose2_kernel(const float* __restrict__ w1,
                                                         unsigned short* __restrict__ w1T,
                                                         const float* __restrict__ w2,
                                                         unsigned short* __restrict__ w2T) {
  __shared__ float tile[64][65];
  const int z = blockIdx.y;
  const int b = blockIdx.x;   // 0..1023
  const float* ip; unsigned short* op; int R, C, r0, c0;
  if (z < 8) {
    const size_t base = (size_t)z * DDIM * FDIM;
    ip = w1 + base; op = w1T + base; R = DDIM; C = FDIM;
    r0 = (b >> 6) << 6; c0 = (b & 63) << 6;           // 16 x 64 tiles; consecutive b -> same rows
  } else {
    const size_t base = (size_t)(z - 8) * DDIM * FDIM;
    ip = w2 + base; op = w2T + base; R = FDIM; C = DDIM;
    r0 = (b & 63) << 6; c0 = (b >> 6) << 6;           // 64 x 16 tiles
  }
  const int tid = threadIdx.x;
  const int rr = tid >> 4;          // 0..15
  const int cc = (tid & 15) << 2;   // 0..60
#pragma unroll
  for (int k = 0; k < 4; ++k) {
    f32x4 v = *(const f32x4*)(ip + (size_t)(r0 + rr + 16 * k) * C + c0 + cc);
    tile[rr + 16 * k][cc + 0] = v[0];
    tile[rr + 16 * k][cc + 1] = v[1];
    tile[rr + 16 * k][cc + 2] = v[2];
    tile[rr + 16 * k][cc + 3] = v[3];
  }
  __syncthreads();
  const int oc = tid >> 3;          // 0..31  (input col = output row)
  const int ob = (tid & 7) << 3;    // 0,8,..,56 — 8 lanes cover the full 64-elem row
#pragma unroll
  for (int k = 0; k < 2; ++k) {
    const int c = oc + 32 * k;
    u16x8 o;
#pragma unroll
    for (int j = 0; j < 8; ++j) o[j] = f2bf(tile[ob + j][c]);
    *(u16x8*)(op + (size_t)(c0 + c) * R + r0 + ob) = o;
  }
}

// ---------- GEMM1 fused: mIdx<32 -> 256-row main (8-phase); else 128-row partial (2-phase) ----------
// grid (48, 16), 512 threads, 128 KiB smem arena shared by both paths
__global__ __launch_bounds__(512, 2) void gemm1_fused(const unsigned short* __restrict__ hB,   // [T][D]
                                                      const unsigned short* __restrict__ w1T,  // [E][F][D]
                                                      const float* __restrict__ b1,            // [E][F]
                                                      const int* __restrict__ g_cnt,
                                                      const int* __restrict__ g_off,
                                                      const int* __restrict__ pairTok,
                                                      const int* __restrict__ b256E,
                                                      const int* __restrict__ b256M,
                                                      const int* __restrict__ b128E,
                                                      const int* __restrict__ b128M,
                                                      const int* __restrict__ nT,
                                                      unsigned short* __restrict__ h1) {       // [P][F]
  __shared__ __align__(16) char smem[131072];
  const int flat = blockIdx.x + 48 * blockIdx.y;        // 0..767, 768%8==0
  const int w = (flat & 7) * 96 + (flat >> 3);          // chunked XCD swizzle (bijective)
  const int mIdx = w % 48;
  const int nB = w / 48;
  const int n0 = nB << 8;

  const int tid = threadIdx.x;
  const int lane = tid & 63;
  const int wm = (tid >> 6) >> 2;    // 0..1
  const int wn = (tid >> 6) & 3;     // 0..3
  const int kh = lane >> 4;          // 0..3
  const int l15 = lane & 15;

  if (mIdx < 32) {
    // ================= MAIN: 256x256, BK=64, 8-phase counted-vmcnt =================
    if (mIdx >= nT[0]) return;
    const int e = b256E[mIdx];
    const int m0 = b256M[mIdx];
    const int off_e = g_off[e];

    // smem: A-half (buf,ks) at ((buf*2+ks)*16384); B-half at 65536 + same
    const unsigned short* gArow[2];
    const unsigned short* gBrow[2];
    int ldsOff[2];
#pragma unroll
    for (int c = 0; c < 2; ++c) {
      const int idx = c * 512 + tid;
      const int row = idx >> 2;
      const int g = (idx & 3) ^ ((row >> 1) & 3);
      ldsOff[c] = idx * 16;
      const int tok = pairTok[off_e + m0 + row];        // full block: no clamp
      gArow[c] = hB + (size_t)tok * DDIM + g * 8;
      gBrow[c] = w1T + ((size_t)e * FDIM + (n0 + row)) * DDIM + g * 8;
    }

#define AH_OFF(bufv, ksv) (((bufv) * 2 + (ksv)) * 16384)
#define BH_OFF(bufv, ksv) (65536 + ((bufv) * 2 + (ksv)) * 16384)
#define G1_STAGE_A(bufv, ksv, kofs) do { \
    gload16(gArow[0] + (kofs), smem + AH_OFF(bufv, ksv) + ldsOff[0]); \
    gload16(gArow[1] + (kofs), smem + AH_OFF(bufv, ksv) + ldsOff[1]); } while (0)
#define G1_STAGE_B(bufv, ksv, kofs) do { \
    gload16(gBrow[0] + (kofs), smem + BH_OFF(bufv, ksv) + ldsOff[0]); \
    gload16(gBrow[1] + (kofs), smem + BH_OFF(bufv, ksv) + ldsOff[1]); } while (0)

    int aoff[8], boff[4];
#pragma unroll
    for (int i = 0; i < 8; ++i) {
      const int r = wm * 128 + i * 16 + l15;
      aoff[i] = r * 64 + ((kh ^ ((r >> 1) & 3)) << 4);
    }
#pragma unroll
    for (int i = 0; i < 4; ++i) {
      const int r = wn * 64 + i * 16 + l15;
      boff[i] = r * 64 + ((kh ^ ((r >> 1) & 3)) << 4);
    }

    f32x4 acc[8][4];
#pragma unroll
    for (int i = 0; i < 8; ++i)
#pragma unroll
      for (int j = 0; j < 4; ++j) acc[i][j] = (f32x4){0.f, 0.f, 0.f, 0.f};

    const int KT = DDIM / 64;   // 16
    G1_STAGE_A(0, 0, 0);  G1_STAGE_B(0, 0, 0);
    G1_STAGE_A(0, 1, 32); G1_STAGE_B(0, 1, 32);
    G1_STAGE_A(1, 0, 64); G1_STAGE_B(1, 0, 64);
    G1_STAGE_A(1, 1, 96);
    WAITV(6);
    BARX();

    for (int t = 0; t < KT; ++t) {
      const int buf = t & 1;
      const int bufn = buf ^ 1;
      const int ko1 = (t + 1) * 64;
      const int ko2 = (t + 2) * 64;
      bf16x8 af[4], bv[4];
#pragma unroll
      for (int ks = 0; ks < 2; ++ks) {
#pragma unroll
        for (int i = 0; i < 4; ++i) bv[i] = *(const bf16x8*)(smem + BH_OFF(buf, ks) + boff[i]);
#pragma unroll
        for (int i = 0; i < 4; ++i) af[i] = *(const bf16x8*)(smem + AH_OFF(buf, ks) + aoff[i]);
        __builtin_amdgcn_s_setprio(1);
#pragma unroll
        for (int mi = 0; mi < 4; ++mi)
#pragma unroll
          for (int ni = 0; ni < 4; ++ni)
            acc[mi][ni] = __builtin_amdgcn_mfma_f32_16x16x32_bf16(af[mi], bv[ni], acc[mi][ni], 0, 0, 0);
        __builtin_amdgcn_s_setprio(0);
        if (ks == 0) { if (t + 1 < KT) G1_STAGE_B(bufn, 1, ko1 + 32); }
        else         { if (t + 2 < KT) G1_STAGE_B(buf, 0, ko2); }
        BARX();
#pragma unroll
        for (int i = 0; i < 4; ++i) af[i] = *(const bf16x8*)(smem + AH_OFF(buf, ks) + aoff[4 + i]);
        __builtin_amdgcn_s_setprio(1);
#pragma unroll
        for (int mi = 0; mi < 4; ++mi)
#pragma unroll
          for (int ni = 0; ni < 4; ++ni)
            acc[4 + mi][ni] = __builtin_amdgcn_mfma_f32_16x16x32_bf16(af[mi], bv[ni], acc[4 + mi][ni], 0, 0, 0);
        __builtin_amdgcn_s_setprio(0);
        if (ks == 0) { if (t + 2 < KT) G1_STAGE_A(buf, 0, ko2); }
        else {
          if (t + 2 < KT) G1_STAGE_A(buf, 1, ko2 + 32);
          if (t < KT - 2)      { WAITV(6); }
          else if (t == KT - 2){ WAITV(0); }
        }
        BARX();
      }
    }
#undef G1_STAGE_A
#undef G1_STAGE_B
#undef AH_OFF
#undef BH_OFF

    float bias[4];
#pragma unroll
    for (int ni = 0; ni < 4; ++ni)
      bias[ni] = b1[e * FDIM + n0 + wn * 64 + ni * 16 + l15];
#pragma unroll
    for (int mi = 0; mi < 8; ++mi) {
#pragma unroll
      for (int j = 0; j < 4; ++j) {
        const int row = wm * 128 + mi * 16 + kh * 4 + j;
        unsigned short* dst = h1 + (size_t)(off_e + m0 + row) * FDIM + n0 + wn * 64;
#pragma unroll
        for (int ni = 0; ni < 4; ++ni)
          dst[ni * 16 + l15] = f2bf(gelu_tanh(acc[mi][ni][j] + bias[ni]));
      }
    }
    return;
  }

  // ================= PARTIAL: 128x256, BK=64, 2-phase (r8 body) =================
  {
    const int mI = mIdx - 32;
    if (mI >= nT[1]) return;
    const int e = b128E[mI];
    const int m0 = b128M[mI];
    const int off_e = g_off[e];
    const int rows_e = min(128, g_cnt[e] - m0);

    unsigned short* As = (unsigned short*)smem;               // 2 x 128x64 = 32 KiB
    unsigned short* Bs = (unsigned short*)(smem + 32768);     // 2 x 256x64 = 64 KiB
    const int ABUF = 128 * 64;   // ushorts per buffer
    const int BBUF = 256 * 64;

    const unsigned short* gA[2];
    const unsigned short* gB[4];
    int ldsA[2], ldsB[4];
#pragma unroll
    for (int c = 0; c < 2; ++c) {
      const int p = (c * 512 + tid) * 16;
      const int row = p >> 7;          // 0..127
      const int g = ((p >> 4) & 7) ^ (row & 7);
      ldsA[c] = p;
      const int tok = pairTok[off_e + m0 + min(row, rows_e - 1)];
      gA[c] = hB + (size_t)tok * DDIM + (g << 3);
    }
#pragma unroll
    for (int c = 0; c < 4; ++c) {
      const int p = (c * 512 + tid) * 16;
      const int row = p >> 7;          // 0..255
      const int g = ((p >> 4) & 7) ^ (row & 7);
      ldsB[c] = p;
      gB[c] = w1T + ((size_t)e * FDIM + (n0 + row)) * DDIM + (g << 3);
    }

    int aoff[4][2], boff[4][2];
#pragma unroll
    for (int i = 0; i < 4; ++i) {
      const int ar = wm * 64 + i * 16 + l15;
      const int br = wn * 64 + i * 16 + l15;
#pragma unroll
      for (int ks = 0; ks < 2; ++ks) {
        aoff[i][ks] = ar * 128 + ((((ks << 2) | kh) ^ (ar & 7)) << 4);
        boff[i][ks] = br * 128 + ((((ks << 2) | kh) ^ (br & 7)) << 4);
      }
    }

    f32x4 acc[4][4];
#pragma unroll
    for (int i = 0; i < 4; ++i)
#pragma unroll
      for (int j = 0; j < 4; ++j) acc[i][j] = (f32x4){0.f, 0.f, 0.f, 0.f};

#pragma unroll
    for (int c = 0; c < 2; ++c) gload16(gA[c], (char*)As + ldsA[c]);
#pragma unroll
    for (int c = 0; c < 4; ++c) gload16(gB[c], (char*)Bs + ldsB[c]);
    WAITV(0);
    BARX();

    int cur = 0;
    const int KT = DDIM / 64;   // 16
    for (int kt = 0; kt < KT; ++kt) {
      if (kt + 1 < KT) {
#pragma unroll
        for (int c = 0; c < 2; ++c) gload16(gA[c] + (size_t)(kt + 1) * 64, (char*)(As + (cur ^ 1) * ABUF) + ldsA[c]);
#pragma unroll
        for (int c = 0; c < 4; ++c) gload16(gB[c] + (size_t)(kt + 1) * 64, (char*)(Bs + (cur ^ 1) * BBUF) + ldsB[c]);
      }
#pragma unroll
      for (int ks = 0; ks < 2; ++ks) {
        bf16x8 af[4], bv[4];
#pragma unroll
        for (int i = 0; i < 4; ++i) af[i] = *(const bf16x8*)((const char*)(As + cur * ABUF) + aoff[i][ks]);
#pragma unroll
        for (int i = 0; i < 4; ++i) bv[i] = *(const bf16x8*)((const char*)(Bs + cur * BBUF) + boff[i][ks]);
        __builtin_amdgcn_s_setprio(1);
#pragma unroll
        for (int mi = 0; mi < 4; ++mi)
#pragma unroll
          for (int ni = 0; ni < 4; ++ni)
            acc[mi][ni] = __builtin_amdgcn_mfma_f32_16x16x32_bf16(af[mi], bv[ni], acc[mi][ni], 0, 0, 0);
        __builtin_amdgcn_s_setprio(0);
      }
      WAITV(0);
      BARX();
      cur ^= 1;
    }

    float bias[4];
#pragma unroll
    for (int ni = 0; ni < 4; ++ni)
      bias[ni] = b1[e * FDIM + n0 + wn * 64 + ni * 16 + l15];
#pragma unroll
    for (int mi = 0; mi < 4; ++mi) {
#pragma unroll
      for (int j = 0; j < 4; ++j) {
        const int row = wm * 64 + mi * 16 + kh * 4 + j;
        if (row < rows_e) {
          unsigned short* dst = h1 + (size_t)(off_e + m0 + row) * FDIM + n0 + wn * 64;
#pragma unroll
          for (int ni = 0; ni < 4; ++ni)
            dst[ni * 16 + l15] = f2bf(gelu_tanh(acc[mi][ni][j] + bias[ni]));
        }
      }
    }
  }
}

// ---------- GEMM2 fused (split-K x2): mIdx<32 -> 256-row main (8-phase); else 128-row partial ----------
// grid (48, 4, 2), 512 threads
__global__ __launch_bounds__(512, 2) void gemm2_fused(const unsigned short* __restrict__ h1,   // [P][F]
                                                      const unsigned short* __restrict__ w2T,  // [E][D][F]
                                                      const float* __restrict__ b2,            // [E][D]
                                                      const int* __restrict__ g_cnt,
                                                      const int* __restrict__ g_off,
                                                      const int* __restrict__ b256E,
                                                      const int* __restrict__ b256M,
                                                      const int* __restrict__ b128E,
                                                      const int* __restrict__ b128M,
                                                      const int* __restrict__ nT,
                                                      float* __restrict__ h2p) {               // [2][P][D]
  __shared__ __align__(16) char smem[131072];
  const int flat = blockIdx.x + 48 * blockIdx.y + 192 * blockIdx.z;  // 0..383, 384%8==0
  const int w = (flat & 7) * 48 + (flat >> 3);
  const int mIdx = w % 48;
  const int rest = w / 48;            // 0..7
  const int nB = rest & 3;
  const int s = rest >> 2;
  const int n0 = nB << 8;
  const int kbase = s * (FDIM / 2);

  const int tid = threadIdx.x;
  const int lane = tid & 63;
  const int wm = (tid >> 6) >> 2;
  const int wn = (tid >> 6) & 3;
  const int kh = lane >> 4;
  const int l15 = lane & 15;

  if (mIdx < 32) {
    // ================= MAIN: 256x256, 8-phase counted-vmcnt =================
    if (mIdx >= nT[0]) return;
    const int e = b256E[mIdx];
    const int m0 = b256M[mIdx];
    const int off_e = g_off[e];

    const unsigned short* gArow[2];
    const unsigned short* gBrow[2];
    int ldsOff[2];
#pragma unroll
    for (int c = 0; c < 2; ++c) {
      const int idx = c * 512 + tid;
      const int row = idx >> 2;
      const int g = (idx & 3) ^ ((row >> 1) & 3);
      ldsOff[c] = idx * 16;
      gArow[c] = h1 + (size_t)(off_e + m0 + row) * FDIM + kbase + g * 8;
      gBrow[c] = w2T + ((size_t)e * DDIM + (n0 + row)) * FDIM + kbase + g * 8;
    }

#define AH_OFF(bufv, ksv) (((bufv) * 2 + (ksv)) * 16384)
#define BH_OFF(bufv, ksv) (65536 + ((bufv) * 2 + (ksv)) * 16384)
#define G2_STAGE_A(bufv, ksv, kofs) do { \
    gload16(gArow[0] + (kofs), smem + AH_OFF(bufv, ksv) + ldsOff[0]); \
    gload16(gArow[1] + (kofs), smem + AH_OFF(bufv, ksv) + ldsOff[1]); } while (0)
#define G2_STAGE_B(bufv, ksv, kofs) do { \
    gload16(gBrow[0] + (kofs), smem + BH_OFF(bufv, ksv) + ldsOff[0]); \
    gload16(gBrow[1] + (kofs), smem + BH_OFF(bufv, ksv) + ldsOff[1]); } while (0)

    int aoff[8], boff[4];
#pragma unroll
    for (int i = 0; i < 8; ++i) {
      const int r = wm * 128 + i * 16 + l15;
      aoff[i] = r * 64 + ((kh ^ ((r >> 1) & 3)) << 4);
    }
#pragma unroll
    for (int i = 0; i < 4; ++i) {
      const int r = wn * 64 + i * 16 + l15;
      boff[i] = r * 64 + ((kh ^ ((r >> 1) & 3)) << 4);
    }

    f32x4 acc[8][4];
#pragma unroll
    for (int i = 0; i < 8; ++i)
#pragma unroll
      for (int j = 0; j < 4; ++j) acc[i][j] = (f32x4){0.f, 0.f, 0.f, 0.f};

    const int KT = (FDIM / 2) / 64;   // 32
    G2_STAGE_A(0, 0, 0);  G2_STAGE_B(0, 0, 0);
    G2_STAGE_A(0, 1, 32); G2_STAGE_B(0, 1, 32);
    G2_STAGE_A(1, 0, 64); G2_STAGE_B(1, 0, 64);
    G2_STAGE_A(1, 1, 96);
    WAITV(6);
    BARX();

    for (int t = 0; t < KT; ++t) {
      const int buf = t & 1;
      const int bufn = buf ^ 1;
      const int ko1 = (t + 1) * 64;
      const int ko2 = (t + 2) * 64;
      bf16x8 af[4], bv[4];
#pragma unroll
      for (int ks = 0; ks < 2; ++ks) {
#pragma unroll
        for (int i = 0; i < 4; ++i) bv[i] = *(const bf16x8*)(smem + BH_OFF(buf, ks) + boff[i]);
#pragma unroll
        for (int i = 0; i < 4; ++i) af[i] = *(const bf16x8*)(smem + AH_OFF(buf, ks) + aoff[i]);
        __builtin_amdgcn_s_setprio(1);
#pragma unroll
        for (int mi = 0; mi < 4; ++mi)
#pragma unroll
          for (int ni = 0; ni < 4; ++ni)
            acc[mi][ni] = __builtin_amdgcn_mfma_f32_16x16x32_bf16(af[mi], bv[ni], acc[mi][ni], 0, 0, 0);
        __builtin_amdgcn_s_setprio(0);
        if (ks == 0) { if (t + 1 < KT) G2_STAGE_B(bufn, 1, ko1 + 32); }
        else         { if (t + 2 < KT) G2_STAGE_B(buf, 0, ko2); }
        BARX();
#pragma unroll
        for (int i = 0; i < 4; ++i) af[i] = *(const bf16x8*)(smem + AH_OFF(buf, ks) + aoff[4 + i]);
        __builtin_amdgcn_s_setprio(1);
#pragma unroll
        for (int mi = 0; mi < 4; ++mi)
#pragma unroll
          for (int ni = 0; ni < 4; ++ni)
            acc[4 + mi][ni] = __builtin_amdgcn_mfma_f32_16x16x32_bf16(af[mi], bv[ni], acc[4 + mi][ni], 0, 0, 0);
        __builtin_amdgcn_s_setprio(0);
        if (ks == 0) { if (t + 2 < KT) G2_STAGE_A(buf, 0, ko2); }
        else {
          if (t + 2 < KT) G2_STAGE_A(buf, 1, ko2 + 32);
          if (t < KT - 2)      { WAITV(6); }
          else if (t == KT - 2){ WAITV(0); }
        }
        BARX();
      }
    }
#undef G2_STAGE_A
#undef G2_STAGE_B
#undef AH_OFF
#undef BH_OFF

    float* outBase = h2p + (size_t)s * PPAIR * DDIM;
#pragma unroll
    for (int mi = 0; mi < 8; ++mi) {
#pragma unroll
      for (int j = 0; j < 4; ++j) {
        const int row = wm * 128 + mi * 16 + kh * 4 + j;
        float* dp = outBase + (size_t)(off_e + m0 + row) * DDIM;
#pragma unroll
        for (int ni = 0; ni < 4; ++ni) {
          const int col = n0 + wn * 64 + ni * 16 + l15;
          float v = acc[mi][ni][j];
          if (s == 0) v += b2[e * DDIM + col];
          dp[col] = v;
        }
      }
    }
    return;
  }

  // ================= PARTIAL: 128x256, 2-phase (r8 body) =================
  {
    const int mI = mIdx - 32;
    if (mI >= nT[1]) return;
    const int e = b128E[mI];
    const int m0 = b128M[mI];
    const int off_e = g_off[e];
    const int rows_e = min(128, g_cnt[e] - m0);

    unsigned short* As = (unsigned short*)smem;               // 2 x 128x64 = 32 KiB
    unsigned short* Bs = (unsigned short*)(smem + 32768);     // 2 x 256x64 = 64 KiB
    const int ABUF = 128 * 64;
    const int BBUF = 256 * 64;

    const unsigned short* gA[2];
    const unsigned short* gB[4];
    int ldsA[2], ldsB[4];
#pragma unroll
    for (int c = 0; c < 2; ++c) {
      const int p = (c * 512 + tid) * 16;
      const int row = p >> 7;
      const int g = ((p >> 4) & 7) ^ (row & 7);
      ldsA[c] = p;
      gA[c] = h1 + (size_t)(off_e + m0 + min(row, rows_e - 1)) * FDIM + kbase + (g << 3);
    }
#pragma unroll
    for (int c = 0; c < 4; ++c) {
      const int p = (c * 512 + tid) * 16;
      const int row = p >> 7;
      const int g = ((p >> 4) & 7) ^ (row & 7);
      ldsB[c] = p;
      gB[c] = w2T + ((size_t)e * DDIM + (n0 + row)) * FDIM + kbase + (g << 3);
    }

    int aoff[4][2], boff[4][2];
#pragma unroll
    for (int i = 0; i < 4; ++i) {
      const int ar = wm * 64 + i * 16 + l15;
      const int br = wn * 64 + i * 16 + l15;
#pragma unroll
      for (int ks = 0; ks < 2; ++ks) {
        aoff[i][ks] = ar * 128 + ((((ks << 2) | kh) ^ (ar & 7)) << 4);
        boff[i][ks] = br * 128 + ((((ks << 2) | kh) ^ (br & 7)) << 4);
      }
    }

    f32x4 acc[4][4];
#pragma unroll
    for (int i = 0; i < 4; ++i)
#pragma unroll
      for (int j = 0; j < 4; ++j) acc[i][j] = (f32x4){0.f, 0.f, 0.f, 0.f};

#pragma unroll
    for (int c = 0; c < 2; ++c) gload16(gA[c], (char*)As + ldsA[c]);
#pragma unroll
    for (int c = 0; c < 4; ++c) gload16(gB[c], (char*)Bs + ldsB[c]);
    WAITV(0);
    BARX();

    int cur = 0;
    const int KT = (FDIM / 2) / 64;   // 32
    for (int kt = 0; kt < KT; ++kt) {
      if (kt + 1 < KT) {
#pragma unroll
        for (int c = 0; c < 2; ++c) gload16(gA[c] + (size_t)(kt + 1) * 64, (char*)(As + (cur ^ 1) * ABUF) + ldsA[c]);
#pragma unroll
        for (int c = 0; c < 4; ++c) gload16(gB[c] + (size_t)(kt + 1) * 64, (char*)(Bs + (cur ^ 1) * BBUF) + ldsB[c]);
      }
#pragma unroll
      for (int ks = 0; ks < 2; ++ks) {
        bf16x8 af[4], bv[4];
#pragma unroll
        for (int i = 0; i < 4; ++i) af[i] = *(const bf16x8*)((const char*)(As + cur * ABUF) + aoff[i][ks]);
#pragma unroll
        for (int i = 0; i < 4; ++i) bv[i] = *(const bf16x8*)((const char*)(Bs + cur * BBUF) + boff[i][ks]);
        __builtin_amdgcn_s_setprio(1);
#pragma unroll
        for (int mi = 0; mi < 4; ++mi)
#pragma unroll
          for (int ni = 0; ni < 4; ++ni)
            acc[mi][ni] = __builtin_amdgcn_mfma_f32_16x16x32_bf16(af[mi], bv[ni], acc[mi][ni], 0, 0, 0);
        __builtin_amdgcn_s_setprio(0);
      }
      WAITV(0);
      BARX();
      cur ^= 1;
    }

    float* outBase = h2p + (size_t)s * PPAIR * DDIM;
#pragma unroll
    for (int mi = 0; mi < 4; ++mi) {
#pragma unroll
      for (int j = 0; j < 4; ++j) {
        const int row = wm * 64 + mi * 16 + kh * 4 + j;
        if (row < rows_e) {
          float* dp = outBase + (size_t)(off_e + m0 + row) * DDIM;
#pragma unroll
          for (int ni = 0; ni < 4; ++ni) {
            const int col = n0 + wn * 64 + ni * 16 + l15;
            float v = acc[mi][ni][j];
            if (s == 0) v += b2[e * DDIM + col];
            dp[col] = v;
          }
        }
      }
    }
  }
}

// ---------- combine ----------
__global__ __launch_bounds__(256) void combine_kernel(const float* __restrict__ h2p,
                                                      const float* __restrict__ ew,
                                                      const int* __restrict__ inv,
                                                      float* __restrict__ out) {
  const int i = blockIdx.x * 256 + threadIdx.x;  // over TTOK*DDIM/4
  const int t = i >> 8;
  const int c = i & 255;
  const int q0 = inv[t * 2], q1 = inv[t * 2 + 1];
  const float wa = ew[t * 2], wb = ew[t * 2 + 1];
  const f32x4* p0 = (const f32x4*)h2p;
  const f32x4* p1 = (const f32x4*)(h2p + (size_t)PPAIR * DDIM);
  f32x4 r = (p0[(size_t)q0 * 256 + c] + p1[(size_t)q0 * 256 + c]) * wa
          + (p0[(size_t)q1 * 256 + c] + p1[(size_t)q1 * 256 + c]) * wb;
  ((f32x4*)out)[i] = r;
}

// ---------- launch ----------
extern "C" void kernel_launch(void* const* d_in, const int* in_sizes, int n_in,
                              void* d_out, int out_size, void* d_ws, size_t ws_size,
                              hipStream_t stream) {
  (void)in_sizes; (void)n_in; (void)out_size; (void)ws_size;
  const float* hidden = (const float*)d_in[0];
  const int*   eidx   = (const int*)d_in[1];
  const float* ew     = (const float*)d_in[2];
  const float* rlog   = (const float*)d_in[3];
  const float* w1     = (const float*)d_in[4];
  const float* b1     = (const float*)d_in[5];
  const float* w2     = (const float*)d_in[6];
  const float* b2     = (const float*)d_in[7];
  float* out = (float*)d_out;

  char* wsb = (char*)d_ws;
  const size_t SZ_W = (size_t)ENUM * DDIM * FDIM * 2;  // 64 MiB (bf16)
  unsigned short* w1T = (unsigned short*)(wsb);
  unsigned short* w2T = (unsigned short*)(wsb + SZ_W);
  unsigned short* hB  = (unsigned short*)(wsb + 2 * SZ_W);
  unsigned short* h1  = (unsigned short*)(wsb + 2 * SZ_W + (size_t)TTOK * DDIM * 2);
  int* g_cnt   = (int*)(wsb + 2 * SZ_W + (size_t)TTOK * DDIM * 2 + (size_t)PPAIR * FDIM * 2);
  int* g_off   = g_cnt + 8;
  int* pairTok = g_off + 8;
  int* inv     = pairTok + PPAIR;
  int* b256E   = inv + PPAIR;
  int* b256M   = b256E + 32;
  int* b128E   = b256M + 32;
  int* b128M   = b128E + 16;
  int* nT      = b128M + 16;
  float* pstats = (float*)(nT + 2);
  // h2p (2 x 8192 x 1024 fp32 = 64 MiB) aliases w1T exactly (dead after gemm1)
  float* h2p = (float*)wsb;

  pre_kernel<<<2065, 256, 0, stream>>>(hidden, hB, rlog, pstats, eidx, g_cnt, g_off,
                                       pairTok, inv, b256E, b256M, b128E, b128M, nT);
  statsB_kernel<<<1, 64, 0, stream>>>(pstats, out);
  transpose2_kernel<<<dim3(1024, 16), 256, 0, stream>>>(w1, w1T, w2, w2T);
  gemm1_fused<<<dim3(48, 16), 512, 0, stream>>>(hB, w1T, b1, g_cnt, g_off, pairTok,
                                                b256E, b256M, b128E, b128M, nT, h1);
  gemm2_fused<<<dim3(48, 4, 2), 512, 0, stream>>>(h1, w2T, b2, g_cnt, g_off,
                                                  b256E, b256M, b128E, b128M, nT, h2p);
  combine_kernel<<<(TTOK * DDIM / 4) / 256, 256, 0, stream>>>(h2p, ew, inv, out);
}

// Round 14
// 320.608 us; speedup vs baseline: 1.0162x; 1.0162x over previous
//
#include <hip/hip_runtime.h>
#include <stddef.h>
#include <stdint.h>

// ---------- problem dims (fixed by setup_inputs) ----------
#define BDIM 2
#define SDIM 2048
#define DDIM 1024
#define FDIM 4096
#define ENUM 8
#define KSEL 2
#define TTOK (BDIM * SDIM)        // 4096 tokens
#define PPAIR (TTOK * KSEL)       // 8192 (token,k) pairs
#define VOUT ((size_t)TTOK * DDIM) // 4194304 floats of "mixed"

typedef float f32x4 __attribute__((ext_vector_type(4)));
typedef short bf16x8 __attribute__((ext_vector_type(8)));
typedef unsigned short u16x8 __attribute__((ext_vector_type(8)));
typedef unsigned short u16x4 __attribute__((ext_vector_type(4)));

#define WAITV(N) asm volatile("s_waitcnt vmcnt(" #N ")" ::: "memory")
#define BARX() asm volatile("s_barrier" ::: "memory")

__device__ __forceinline__ unsigned short f2bf(float f) {
  unsigned int u = __float_as_uint(f);
  u += 0x7fffu + ((u >> 16) & 1u);   // RNE
  return (unsigned short)(u >> 16);
}

__device__ __forceinline__ float gelu_tanh(float x) {
  float u = 0.7978845608028654f * (x + 0.044715f * x * x * x);
  float e = __expf(2.0f * u);
  float t = 1.0f - 2.0f / (e + 1.0f);   // tanh(u), safe at +-inf
  return 0.5f * x * (1.0f + t);
}

__device__ __forceinline__ void gload16(const void* g, void* l) {
  __builtin_amdgcn_global_load_lds(
      (const __attribute__((address_space(1))) unsigned int*)g,
      (__attribute__((address_space(3))) unsigned int*)l, 16, 0, 0);
}

// ---------- fused pre: cvt_hidden (b<2048) + statsA (2048..2063) + routing (2064)
//                        + w1 transpose (2065..10256) ----------
__global__ __launch_bounds__(256) void pre_kernel(const float* __restrict__ hidden,
                                                  unsigned short* __restrict__ hB,
                                                  const float* __restrict__ lg,
                                                  float* __restrict__ pst,
                                                  const int* __restrict__ eidx,
                                                  int* __restrict__ g_cnt,
                                                  int* __restrict__ g_off,
                                                  int* __restrict__ pairTok,
                                                  int* __restrict__ inv,
                                                  int* __restrict__ b256E,
                                                  int* __restrict__ b256M,
                                                  int* __restrict__ b128E,
                                                  int* __restrict__ b128M,
                                                  int* __restrict__ nT,
                                                  const float* __restrict__ w1,
                                                  unsigned short* __restrict__ w1T) {
  const int b = blockIdx.x;
  const int tid = threadIdx.x;
  if (b < 2048) {
    // hidden fp32 -> bf16 (8 elems/thread)
    const int i = b * 256 + tid;
    f32x4 a = ((const f32x4*)hidden)[(size_t)i * 2];
    f32x4 c = ((const f32x4*)hidden)[(size_t)i * 2 + 1];
    u16x8 o;
    o[0] = f2bf(a[0]); o[1] = f2bf(a[1]); o[2] = f2bf(a[2]); o[3] = f2bf(a[3]);
    o[4] = f2bf(c[0]); o[5] = f2bf(c[1]); o[6] = f2bf(c[2]); o[7] = f2bf(c[3]);
    ((u16x8*)hB)[i] = o;
    return;
  }
  if (b < 2064) {
    // statsA
    __shared__ float se[256], sm[256];
    const int r = (b - 2048) * 256 + tid;
    float v[ENUM];
    float mx = -1e30f;
#pragma unroll
    for (int i = 0; i < ENUM; ++i) { v[i] = lg[r * ENUM + i]; mx = fmaxf(mx, v[i]); }
    float s = 0.f;
#pragma unroll
    for (int i = 0; i < ENUM; ++i) { v[i] = __expf(v[i] - mx); s += v[i]; }
    float invs = 1.f / s;
    float p1 = -1.f, p2 = -1.f, e_ = 0.f;
#pragma unroll
    for (int i = 0; i < ENUM; ++i) {
      float p = v[i] * invs;
      e_ -= p * logf(fmaxf(p, 1e-9f));
      if (p > p1) { p2 = p1; p1 = p; } else if (p > p2) { p2 = p; }
    }
    se[tid] = e_; sm[tid] = p1 - p2;
    __syncthreads();
    for (int st = 128; st > 0; st >>= 1) {
      if (tid < (unsigned)st) { se[tid] += se[tid + st]; sm[tid] += sm[tid + st]; }
      __syncthreads();
    }
    if (tid == 0) { pst[(b - 2048) * 2] = se[0]; pst[(b - 2048) * 2 + 1] = sm[0]; }
    return;
  }
  if (b == 2064) {
    // routing (single block)
    __shared__ int sc[ENUM], so[ENUM], scur[ENUM];
    if (tid < ENUM) sc[tid] = 0;
    __syncthreads();
    for (int p = tid; p < PPAIR; p += 256) atomicAdd(&sc[eidx[p]], 1);
    __syncthreads();
    if (tid == 0) {
      int o = 0, n256 = 0, n128 = 0;
      for (int e = 0; e < ENUM; ++e) {
        so[e] = o;
        const int cnt = sc[e];
        const int nf = cnt >> 8;              // full 256-row blocks
        const int rem = cnt - (nf << 8);
        for (int i = 0; i < nf; ++i) { b256E[n256] = e; b256M[n256] = i << 8; ++n256; }
        const int np = (rem + 127) >> 7;      // 0..2 partial 128-row blocks
        for (int j = 0; j < np; ++j) { b128E[n128] = e; b128M[n128] = (nf << 8) + (j << 7); ++n128; }
        o += cnt;
      }
      nT[0] = n256; nT[1] = n128;             // n256 <= 32, n128 <= 16
    }
    __syncthreads();
    if (tid < ENUM) { scur[tid] = so[tid]; g_cnt[tid] = sc[tid]; g_off[tid] = so[tid]; }
    __syncthreads();
    for (int p = tid; p < PPAIR; p += 256) {
      int e = eidx[p];
      int pos = atomicAdd(&scur[e], 1);
      pairTok[pos] = p >> 1;  // token id
      inv[p] = pos;           // grouped position of pair p
    }
    return;
  }
  // ---- w1 transpose+convert, 64x64 tiles: [1024][4096] -> [4096][1024] per expert ----
  {
    __shared__ float tile[64][65];
    const int t = b - 2065;             // 0..8191
    const int z = t >> 10;              // expert
    const int bb = t & 1023;
    const size_t base = (size_t)z * DDIM * FDIM;
    const float* ip = w1 + base;
    unsigned short* op = w1T + base;
    const int r0 = (bb >> 6) << 6;      // D rows (16 values)
    const int c0 = (bb & 63) << 6;      // F cols (64 values)
    const int rr = tid >> 4;            // 0..15
    const int cc = (tid & 15) << 2;     // 0..60
#pragma unroll
    for (int k = 0; k < 4; ++k) {
      f32x4 v = *(const f32x4*)(ip + (size_t)(r0 + rr + 16 * k) * FDIM + c0 + cc);
      tile[rr + 16 * k][cc + 0] = v[0];
      tile[rr + 16 * k][cc + 1] = v[1];
      tile[rr + 16 * k][cc + 2] = v[2];
      tile[rr + 16 * k][cc + 3] = v[3];
    }
    __syncthreads();
    const int oc = tid >> 3;            // 0..31
    const int ob = (tid & 7) << 3;      // 0..56
#pragma unroll
    for (int k = 0; k < 2; ++k) {
      const int c = oc + 32 * k;
      u16x8 o;
#pragma unroll
      for (int j = 0; j < 8; ++j) o[j] = f2bf(tile[ob + j][c]);
      *(u16x8*)(op + (size_t)(c0 + c) * DDIM + r0 + ob) = o;
    }
  }
}

// ---------- router stats, stage B ----------
__global__ void statsB_kernel(const float* __restrict__ pst, float* __restrict__ out) {
  if (threadIdx.x == 0) {
    float a = 0.f, b = 0.f;
    for (int i = 0; i < 16; ++i) { a += pst[2 * i]; b += pst[2 * i + 1]; }
    out[VOUT]     = a / (float)TTOK;
    out[VOUT + 1] = b / (float)TTOK;
  }
}

// ---------- GEMM1 fused + w2 transpose backfill ----------
// grid (48, 16+171), 512 threads, 128 KiB smem arena
// y<16: mIdx<32 -> 256-row main (8-phase); else 128-row partial (2-phase)
// y>=16: w2 transpose tiles (fill gemm gen-2 idle slots; w2T consumed only by gemm2)
__global__ __launch_bounds__(512, 2) void gemm1_fused(const unsigned short* __restrict__ hB,   // [T][D]
                                                      const unsigned short* __restrict__ w1T,  // [E][F][D]
                                                      const float* __restrict__ b1,            // [E][F]
                                                      const int* __restrict__ g_cnt,
                                                      const int* __restrict__ g_off,
                                                      const int* __restrict__ pairTok,
                                                      const int* __restrict__ b256E,
                                                      const int* __restrict__ b256M,
                                                      const int* __restrict__ b128E,
                                                      const int* __restrict__ b128M,
                                                      const int* __restrict__ nT,
                                                      unsigned short* __restrict__ h1,         // [P][F]
                                                      const float* __restrict__ w2,
                                                      unsigned short* __restrict__ w2T) {
  __shared__ __align__(16) char smem[131072];
  const int tid = threadIdx.x;

  if (blockIdx.y >= 16) {
    // ---- w2 transpose+convert, 64x64 tiles: [4096][1024] -> [1024][4096] per expert ----
    const int t = blockIdx.x + 48 * (blockIdx.y - 16);   // 0..8207
    if (t >= 8192) return;
    float* tile = (float*)smem;                          // [64][65]
    const int z = t >> 10;
    const int bb = t & 1023;
    const size_t base = (size_t)z * DDIM * FDIM;
    const float* ip = w2 + base;
    unsigned short* op = w2T + base;
    const int r0 = (bb & 63) << 6;      // F rows (64 values)
    const int c0 = (bb >> 6) << 6;      // D cols (16 values)
    const int rr = tid >> 3;            // 0..63
    const int cc8 = (tid & 7) << 3;     // 0..56
    {
      const float* src = ip + (size_t)(r0 + rr) * DDIM + c0 + cc8;
      f32x4 v0 = *(const f32x4*)(src);
      f32x4 v1 = *(const f32x4*)(src + 4);
      float* tr = tile + rr * 65 + cc8;
      tr[0] = v0[0]; tr[1] = v0[1]; tr[2] = v0[2]; tr[3] = v0[3];
      tr[4] = v1[0]; tr[5] = v1[1]; tr[6] = v1[2]; tr[7] = v1[3];
    }
    __syncthreads();
    {
      const int oc = tid >> 3;          // 0..63 (output row = input col)
      const int ob = (tid & 7) << 3;    // 0..56
      u16x8 o;
#pragma unroll
      for (int j = 0; j < 8; ++j) o[j] = f2bf(tile[(ob + j) * 65 + oc]);
      *(u16x8*)(op + (size_t)(c0 + oc) * FDIM + r0 + ob) = o;
    }
    return;
  }

  const int flat = blockIdx.x + 48 * blockIdx.y;        // 0..767, 768%8==0
  const int w = (flat & 7) * 96 + (flat >> 3);          // chunked XCD swizzle (bijective)
  const int mIdx = w % 48;
  const int nB = w / 48;
  const int n0 = nB << 8;

  const int lane = tid & 63;
  const int wm = (tid >> 6) >> 2;    // 0..1
  const int wn = (tid >> 6) & 3;     // 0..3
  const int kh = lane >> 4;          // 0..3
  const int l15 = lane & 15;

  if (mIdx < 32) {
    // ================= MAIN: 256x256, BK=64, 8-phase counted-vmcnt =================
    if (mIdx >= nT[0]) return;
    const int e = b256E[mIdx];
    const int m0 = b256M[mIdx];
    const int off_e = g_off[e];

    const unsigned short* gArow[2];
    const unsigned short* gBrow[2];
    int ldsOff[2];
#pragma unroll
    for (int c = 0; c < 2; ++c) {
      const int idx = c * 512 + tid;
      const int row = idx >> 2;
      const int g = (idx & 3) ^ ((row >> 1) & 3);
      ldsOff[c] = idx * 16;
      const int tok = pairTok[off_e + m0 + row];        // full block: no clamp
      gArow[c] = hB + (size_t)tok * DDIM + g * 8;
      gBrow[c] = w1T + ((size_t)e * FDIM + (n0 + row)) * DDIM + g * 8;
    }

#define AH_OFF(bufv, ksv) (((bufv) * 2 + (ksv)) * 16384)
#define BH_OFF(bufv, ksv) (65536 + ((bufv) * 2 + (ksv)) * 16384)
#define G1_STAGE_A(bufv, ksv, kofs) do { \
    gload16(gArow[0] + (kofs), smem + AH_OFF(bufv, ksv) + ldsOff[0]); \
    gload16(gArow[1] + (kofs), smem + AH_OFF(bufv, ksv) + ldsOff[1]); } while (0)
#define G1_STAGE_B(bufv, ksv, kofs) do { \
    gload16(gBrow[0] + (kofs), smem + BH_OFF(bufv, ksv) + ldsOff[0]); \
    gload16(gBrow[1] + (kofs), smem + BH_OFF(bufv, ksv) + ldsOff[1]); } while (0)

    int aoff[8], boff[4];
#pragma unroll
    for (int i = 0; i < 8; ++i) {
      const int r = wm * 128 + i * 16 + l15;
      aoff[i] = r * 64 + ((kh ^ ((r >> 1) & 3)) << 4);
    }
#pragma unroll
    for (int i = 0; i < 4; ++i) {
      const int r = wn * 64 + i * 16 + l15;
      boff[i] = r * 64 + ((kh ^ ((r >> 1) & 3)) << 4);
    }

    f32x4 acc[8][4];
#pragma unroll
    for (int i = 0; i < 8; ++i)
#pragma unroll
      for (int j = 0; j < 4; ++j) acc[i][j] = (f32x4){0.f, 0.f, 0.f, 0.f};

    const int KT = DDIM / 64;   // 16
    G1_STAGE_A(0, 0, 0);  G1_STAGE_B(0, 0, 0);
    G1_STAGE_A(0, 1, 32); G1_STAGE_B(0, 1, 32);
    G1_STAGE_A(1, 0, 64); G1_STAGE_B(1, 0, 64);
    G1_STAGE_A(1, 1, 96);
    WAITV(6);
    BARX();

    for (int t = 0; t < KT; ++t) {
      const int buf = t & 1;
      const int bufn = buf ^ 1;
      const int ko1 = (t + 1) * 64;
      const int ko2 = (t + 2) * 64;
      bf16x8 af[4], bv[4];
#pragma unroll
      for (int ks = 0; ks < 2; ++ks) {
#pragma unroll
        for (int i = 0; i < 4; ++i) bv[i] = *(const bf16x8*)(smem + BH_OFF(buf, ks) + boff[i]);
#pragma unroll
        for (int i = 0; i < 4; ++i) af[i] = *(const bf16x8*)(smem + AH_OFF(buf, ks) + aoff[i]);
        __builtin_amdgcn_s_setprio(1);
#pragma unroll
        for (int mi = 0; mi < 4; ++mi)
#pragma unroll
          for (int ni = 0; ni < 4; ++ni)
            acc[mi][ni] = __builtin_amdgcn_mfma_f32_16x16x32_bf16(af[mi], bv[ni], acc[mi][ni], 0, 0, 0);
        __builtin_amdgcn_s_setprio(0);
        if (ks == 0) { if (t + 1 < KT) G1_STAGE_B(bufn, 1, ko1 + 32); }
        else         { if (t + 2 < KT) G1_STAGE_B(buf, 0, ko2); }
        BARX();
#pragma unroll
        for (int i = 0; i < 4; ++i) af[i] = *(const bf16x8*)(smem + AH_OFF(buf, ks) + aoff[4 + i]);
        __builtin_amdgcn_s_setprio(1);
#pragma unroll
        for (int mi = 0; mi < 4; ++mi)
#pragma unroll
          for (int ni = 0; ni < 4; ++ni)
            acc[4 + mi][ni] = __builtin_amdgcn_mfma_f32_16x16x32_bf16(af[mi], bv[ni], acc[4 + mi][ni], 0, 0, 0);
        __builtin_amdgcn_s_setprio(0);
        if (ks == 0) { if (t + 2 < KT) G1_STAGE_A(buf, 0, ko2); }
        else {
          if (t + 2 < KT) G1_STAGE_A(buf, 1, ko2 + 32);
          if (t < KT - 2)      { WAITV(6); }
          else if (t == KT - 2){ WAITV(0); }
        }
        BARX();
      }
    }
#undef G1_STAGE_A
#undef G1_STAGE_B
#undef AH_OFF
#undef BH_OFF

    float bias[4];
#pragma unroll
    for (int ni = 0; ni < 4; ++ni)
      bias[ni] = b1[e * FDIM + n0 + wn * 64 + ni * 16 + l15];
#pragma unroll
    for (int mi = 0; mi < 8; ++mi) {
#pragma unroll
      for (int j = 0; j < 4; ++j) {
        const int row = wm * 128 + mi * 16 + kh * 4 + j;
        unsigned short* dst = h1 + (size_t)(off_e + m0 + row) * FDIM + n0 + wn * 64;
#pragma unroll
        for (int ni = 0; ni < 4; ++ni)
          dst[ni * 16 + l15] = f2bf(gelu_tanh(acc[mi][ni][j] + bias[ni]));
      }
    }
    return;
  }

  // ================= PARTIAL: 128x256, BK=64, 2-phase =================
  {
    const int mI = mIdx - 32;
    if (mI >= nT[1]) return;
    const int e = b128E[mI];
    const int m0 = b128M[mI];
    const int off_e = g_off[e];
    const int rows_e = min(128, g_cnt[e] - m0);

    unsigned short* As = (unsigned short*)smem;               // 2 x 128x64 = 32 KiB
    unsigned short* Bs = (unsigned short*)(smem + 32768);     // 2 x 256x64 = 64 KiB
    const int ABUF = 128 * 64;   // ushorts per buffer
    const int BBUF = 256 * 64;

    const unsigned short* gA[2];
    const unsigned short* gB[4];
    int ldsA[2], ldsB[4];
#pragma unroll
    for (int c = 0; c < 2; ++c) {
      const int p = (c * 512 + tid) * 16;
      const int row = p >> 7;          // 0..127
      const int g = ((p >> 4) & 7) ^ (row & 7);
      ldsA[c] = p;
      const int tok = pairTok[off_e + m0 + min(row, rows_e - 1)];
      gA[c] = hB + (size_t)tok * DDIM + (g << 3);
    }
#pragma unroll
    for (int c = 0; c < 4; ++c) {
      const int p = (c * 512 + tid) * 16;
      const int row = p >> 7;          // 0..255
      const int g = ((p >> 4) & 7) ^ (row & 7);
      ldsB[c] = p;
      gB[c] = w1T + ((size_t)e * FDIM + (n0 + row)) * DDIM + (g << 3);
    }

    int aoff[4][2], boff[4][2];
#pragma unroll
    for (int i = 0; i < 4; ++i) {
      const int ar = wm * 64 + i * 16 + l15;
      const int br = wn * 64 + i * 16 + l15;
#pragma unroll
      for (int ks = 0; ks < 2; ++ks) {
        aoff[i][ks] = ar * 128 + ((((ks << 2) | kh) ^ (ar & 7)) << 4);
        boff[i][ks] = br * 128 + ((((ks << 2) | kh) ^ (br & 7)) << 4);
      }
    }

    f32x4 acc[4][4];
#pragma unroll
    for (int i = 0; i < 4; ++i)
#pragma unroll
      for (int j = 0; j < 4; ++j) acc[i][j] = (f32x4){0.f, 0.f, 0.f, 0.f};

#pragma unroll
    for (int c = 0; c < 2; ++c) gload16(gA[c], (char*)As + ldsA[c]);
#pragma unroll
    for (int c = 0; c < 4; ++c) gload16(gB[c], (char*)Bs + ldsB[c]);
    WAITV(0);
    BARX();

    int cur = 0;
    const int KT = DDIM / 64;   // 16
    for (int kt = 0; kt < KT; ++kt) {
      if (kt + 1 < KT) {
#pragma unroll
        for (int c = 0; c < 2; ++c) gload16(gA[c] + (size_t)(kt + 1) * 64, (char*)(As + (cur ^ 1) * ABUF) + ldsA[c]);
#pragma unroll
        for (int c = 0; c < 4; ++c) gload16(gB[c] + (size_t)(kt + 1) * 64, (char*)(Bs + (cur ^ 1) * BBUF) + ldsB[c]);
      }
#pragma unroll
      for (int ks = 0; ks < 2; ++ks) {
        bf16x8 af[4], bv[4];
#pragma unroll
        for (int i = 0; i < 4; ++i) af[i] = *(const bf16x8*)((const char*)(As + cur * ABUF) + aoff[i][ks]);
#pragma unroll
        for (int i = 0; i < 4; ++i) bv[i] = *(const bf16x8*)((const char*)(Bs + cur * BBUF) + boff[i][ks]);
        __builtin_amdgcn_s_setprio(1);
#pragma unroll
        for (int mi = 0; mi < 4; ++mi)
#pragma unroll
          for (int ni = 0; ni < 4; ++ni)
            acc[mi][ni] = __builtin_amdgcn_mfma_f32_16x16x32_bf16(af[mi], bv[ni], acc[mi][ni], 0, 0, 0);
        __builtin_amdgcn_s_setprio(0);
      }
      WAITV(0);
      BARX();
      cur ^= 1;
    }

    float bias[4];
#pragma unroll
    for (int ni = 0; ni < 4; ++ni)
      bias[ni] = b1[e * FDIM + n0 + wn * 64 + ni * 16 + l15];
#pragma unroll
    for (int mi = 0; mi < 4; ++mi) {
#pragma unroll
      for (int j = 0; j < 4; ++j) {
        const int row = wm * 64 + mi * 16 + kh * 4 + j;
        if (row < rows_e) {
          unsigned short* dst = h1 + (size_t)(off_e + m0 + row) * FDIM + n0 + wn * 64;
#pragma unroll
          for (int ni = 0; ni < 4; ++ni)
            dst[ni * 16 + l15] = f2bf(gelu_tanh(acc[mi][ni][j] + bias[ni]));
        }
      }
    }
  }
}

// ---------- GEMM2 fused (split-K x2): mIdx<32 -> 256-row main (8-phase); else 128-row partial ----------
// grid (48, 4, 2), 512 threads
__global__ __launch_bounds__(512, 2) void gemm2_fused(const unsigned short* __restrict__ h1,   // [P][F]
                                                      const unsigned short* __restrict__ w2T,  // [E][D][F]
                                                      const float* __restrict__ b2,            // [E][D]
                                                      const int* __restrict__ g_cnt,
                                                      const int* __restrict__ g_off,
                                                      const int* __restrict__ b256E,
                                                      const int* __restrict__ b256M,
                                                      const int* __restrict__ b128E,
                                                      const int* __restrict__ b128M,
                                                      const int* __restrict__ nT,
                                                      float* __restrict__ h2p) {               // [2][P][D]
  __shared__ __align__(16) char smem[131072];
  const int flat = blockIdx.x + 48 * blockIdx.y + 192 * blockIdx.z;  // 0..383, 384%8==0
  const int w = (flat & 7) * 48 + (flat >> 3);
  const int mIdx = w % 48;
  const int rest = w / 48;            // 0..7
  const int nB = rest & 3;
  const int s = rest >> 2;
  const int n0 = nB << 8;
  const int kbase = s * (FDIM / 2);

  const int tid = threadIdx.x;
  const int lane = tid & 63;
  const int wm = (tid >> 6) >> 2;
  const int wn = (tid >> 6) & 3;
  const int kh = lane >> 4;
  const int l15 = lane & 15;

  if (mIdx < 32) {
    // ================= MAIN: 256x256, 8-phase counted-vmcnt =================
    if (mIdx >= nT[0]) return;
    const int e = b256E[mIdx];
    const int m0 = b256M[mIdx];
    const int off_e = g_off[e];

    const unsigned short* gArow[2];
    const unsigned short* gBrow[2];
    int ldsOff[2];
#pragma unroll
    for (int c = 0; c < 2; ++c) {
      const int idx = c * 512 + tid;
      const int row = idx >> 2;
      const int g = (idx & 3) ^ ((row >> 1) & 3);
      ldsOff[c] = idx * 16;
      gArow[c] = h1 + (size_t)(off_e + m0 + row) * FDIM + kbase + g * 8;
      gBrow[c] = w2T + ((size_t)e * DDIM + (n0 + row)) * FDIM + kbase + g * 8;
    }

#define AH_OFF(bufv, ksv) (((bufv) * 2 + (ksv)) * 16384)
#define BH_OFF(bufv, ksv) (65536 + ((bufv) * 2 + (ksv)) * 16384)
#define G2_STAGE_A(bufv, ksv, kofs) do { \
    gload16(gArow[0] + (kofs), smem + AH_OFF(bufv, ksv) + ldsOff[0]); \
    gload16(gArow[1] + (kofs), smem + AH_OFF(bufv, ksv) + ldsOff[1]); } while (0)
#define G2_STAGE_B(bufv, ksv, kofs) do { \
    gload16(gBrow[0] + (kofs), smem + BH_OFF(bufv, ksv) + ldsOff[0]); \
    gload16(gBrow[1] + (kofs), smem + BH_OFF(bufv, ksv) + ldsOff[1]); } while (0)

    int aoff[8], boff[4];
#pragma unroll
    for (int i = 0; i < 8; ++i) {
      const int r = wm * 128 + i * 16 + l15;
      aoff[i] = r * 64 + ((kh ^ ((r >> 1) & 3)) << 4);
    }
#pragma unroll
    for (int i = 0; i < 4; ++i) {
      const int r = wn * 64 + i * 16 + l15;
      boff[i] = r * 64 + ((kh ^ ((r >> 1) & 3)) << 4);
    }

    f32x4 acc[8][4];
#pragma unroll
    for (int i = 0; i < 8; ++i)
#pragma unroll
      for (int j = 0; j < 4; ++j) acc[i][j] = (f32x4){0.f, 0.f, 0.f, 0.f};

    const int KT = (FDIM / 2) / 64;   // 32
    G2_STAGE_A(0, 0, 0);  G2_STAGE_B(0, 0, 0);
    G2_STAGE_A(0, 1, 32); G2_STAGE_B(0, 1, 32);
    G2_STAGE_A(1, 0, 64); G2_STAGE_B(1, 0, 64);
    G2_STAGE_A(1, 1, 96);
    WAITV(6);
    BARX();

    for (int t = 0; t < KT; ++t) {
      const int buf = t & 1;
      const int bufn = buf ^ 1;
      const int ko1 = (t + 1) * 64;
      const int ko2 = (t + 2) * 64;
      bf16x8 af[4], bv[4];
#pragma unroll
      for (int ks = 0; ks < 2; ++ks) {
#pragma unroll
        for (int i = 0; i < 4; ++i) bv[i] = *(const bf16x8*)(smem + BH_OFF(buf, ks) + boff[i]);
#pragma unroll
        for (int i = 0; i < 4; ++i) af[i] = *(const bf16x8*)(smem + AH_OFF(buf, ks) + aoff[i]);
        __builtin_amdgcn_s_setprio(1);
#pragma unroll
        for (int mi = 0; mi < 4; ++mi)
#pragma unroll
          for (int ni = 0; ni < 4; ++ni)
            acc[mi][ni] = __builtin_amdgcn_mfma_f32_16x16x32_bf16(af[mi], bv[ni], acc[mi][ni], 0, 0, 0);
        __builtin_amdgcn_s_setprio(0);
        if (ks == 0) { if (t + 1 < KT) G2_STAGE_B(bufn, 1, ko1 + 32); }
        else         { if (t + 2 < KT) G2_STAGE_B(buf, 0, ko2); }
        BARX();
#pragma unroll
        for (int i = 0; i < 4; ++i) af[i] = *(const bf16x8*)(smem + AH_OFF(buf, ks) + aoff[4 + i]);
        __builtin_amdgcn_s_setprio(1);
#pragma unroll
        for (int mi = 0; mi < 4; ++mi)
#pragma unroll
          for (int ni = 0; ni < 4; ++ni)
            acc[4 + mi][ni] = __builtin_amdgcn_mfma_f32_16x16x32_bf16(af[mi], bv[ni], acc[4 + mi][ni], 0, 0, 0);
        __builtin_amdgcn_s_setprio(0);
        if (ks == 0) { if (t + 2 < KT) G2_STAGE_A(buf, 0, ko2); }
        else {
          if (t + 2 < KT) G2_STAGE_A(buf, 1, ko2 + 32);
          if (t < KT - 2)      { WAITV(6); }
          else if (t == KT - 2){ WAITV(0); }
        }
        BARX();
      }
    }
#undef G2_STAGE_A
#undef G2_STAGE_B
#undef AH_OFF
#undef BH_OFF

    float* outBase = h2p + (size_t)s * PPAIR * DDIM;
#pragma unroll
    for (int mi = 0; mi < 8; ++mi) {
#pragma unroll
      for (int j = 0; j < 4; ++j) {
        const int row = wm * 128 + mi * 16 + kh * 4 + j;
        float* dp = outBase + (size_t)(off_e + m0 + row) * DDIM;
#pragma unroll
        for (int ni = 0; ni < 4; ++ni) {
          const int col = n0 + wn * 64 + ni * 16 + l15;
          float v = acc[mi][ni][j];
          if (s == 0) v += b2[e * DDIM + col];
          dp[col] = v;
        }
      }
    }
    return;
  }

  // ================= PARTIAL: 128x256, 2-phase =================
  {
    const int mI = mIdx - 32;
    if (mI >= nT[1]) return;
    const int e = b128E[mI];
    const int m0 = b128M[mI];
    const int off_e = g_off[e];
    const int rows_e = min(128, g_cnt[e] - m0);

    unsigned short* As = (unsigned short*)smem;               // 2 x 128x64 = 32 KiB
    unsigned short* Bs = (unsigned short*)(smem + 32768);     // 2 x 256x64 = 64 KiB
    const int ABUF = 128 * 64;
    const int BBUF = 256 * 64;

    const unsigned short* gA[2];
    const unsigned short* gB[4];
    int ldsA[2], ldsB[4];
#pragma unroll
    for (int c = 0; c < 2; ++c) {
      const int p = (c * 512 + tid) * 16;
      const int row = p >> 7;
      const int g = ((p >> 4) & 7) ^ (row & 7);
      ldsA[c] = p;
      gA[c] = h1 + (size_t)(off_e + m0 + min(row, rows_e - 1)) * FDIM + kbase + (g << 3);
    }
#pragma unroll
    for (int c = 0; c < 4; ++c) {
      const int p = (c * 512 + tid) * 16;
      const int row = p >> 7;
      const int g = ((p >> 4) & 7) ^ (row & 7);
      ldsB[c] = p;
      gB[c] = w2T + ((size_t)e * DDIM + (n0 + row)) * FDIM + kbase + (g << 3);
    }

    int aoff[4][2], boff[4][2];
#pragma unroll
    for (int i = 0; i < 4; ++i) {
      const int ar = wm * 64 + i * 16 + l15;
      const int br = wn * 64 + i * 16 + l15;
#pragma unroll
      for (int ks = 0; ks < 2; ++ks) {
        aoff[i][ks] = ar * 128 + ((((ks << 2) | kh) ^ (ar & 7)) << 4);
        boff[i][ks] = br * 128 + ((((ks << 2) | kh) ^ (br & 7)) << 4);
      }
    }

    f32x4 acc[4][4];
#pragma unroll
    for (int i = 0; i < 4; ++i)
#pragma unroll
      for (int j = 0; j < 4; ++j) acc[i][j] = (f32x4){0.f, 0.f, 0.f, 0.f};

#pragma unroll
    for (int c = 0; c < 2; ++c) gload16(gA[c], (char*)As + ldsA[c]);
#pragma unroll
    for (int c = 0; c < 4; ++c) gload16(gB[c], (char*)Bs + ldsB[c]);
    WAITV(0);
    BARX();

    int cur = 0;
    const int KT = (FDIM / 2) / 64;   // 32
    for (int kt = 0; kt < KT; ++kt) {
      if (kt + 1 < KT) {
#pragma unroll
        for (int c = 0; c < 2; ++c) gload16(gA[c] + (size_t)(kt + 1) * 64, (char*)(As + (cur ^ 1) * ABUF) + ldsA[c]);
#pragma unroll
        for (int c = 0; c < 4; ++c) gload16(gB[c] + (size_t)(kt + 1) * 64, (char*)(Bs + (cur ^ 1) * BBUF) + ldsB[c]);
      }
#pragma unroll
      for (int ks = 0; ks < 2; ++ks) {
        bf16x8 af[4], bv[4];
#pragma unroll
        for (int i = 0; i < 4; ++i) af[i] = *(const bf16x8*)((const char*)(As + cur * ABUF) + aoff[i][ks]);
#pragma unroll
        for (int i = 0; i < 4; ++i) bv[i] = *(const bf16x8*)((const char*)(Bs + cur * BBUF) + boff[i][ks]);
        __builtin_amdgcn_s_setprio(1);
#pragma unroll
        for (int mi = 0; mi < 4; ++mi)
#pragma unroll
          for (int ni = 0; ni < 4; ++ni)
            acc[mi][ni] = __builtin_amdgcn_mfma_f32_16x16x32_bf16(af[mi], bv[ni], acc[mi][ni], 0, 0, 0);
        __builtin_amdgcn_s_setprio(0);
      }
      WAITV(0);
      BARX();
      cur ^= 1;
    }

    float* outBase = h2p + (size_t)s * PPAIR * DDIM;
#pragma unroll
    for (int mi = 0; mi < 4; ++mi) {
#pragma unroll
      for (int j = 0; j < 4; ++j) {
        const int row = wm * 64 + mi * 16 + kh * 4 + j;
        if (row < rows_e) {
          float* dp = outBase + (size_t)(off_e + m0 + row) * DDIM;
#pragma unroll
          for (int ni = 0; ni < 4; ++ni) {
            const int col = n0 + wn * 64 + ni * 16 + l15;
            float v = acc[mi][ni][j];
            if (s == 0) v += b2[e * DDIM + col];
            dp[col] = v;
          }
        }
      }
    }
  }
}

// ---------- combine ----------
__global__ __launch_bounds__(256) void combine_kernel(const float* __restrict__ h2p,
                                                      const float* __restrict__ ew,
                                                      const int* __restrict__ inv,
                                                      float* __restrict__ out) {
  const int i = blockIdx.x * 256 + threadIdx.x;  // over TTOK*DDIM/4
  const int t = i >> 8;
  const int c = i & 255;
  const int q0 = inv[t * 2], q1 = inv[t * 2 + 1];
  const float wa = ew[t * 2], wb = ew[t * 2 + 1];
  const f32x4* p0 = (const f32x4*)h2p;
  const f32x4* p1 = (const f32x4*)(h2p + (size_t)PPAIR * DDIM);
  f32x4 r = (p0[(size_t)q0 * 256 + c] + p1[(size_t)q0 * 256 + c]) * wa
          + (p0[(size_t)q1 * 256 + c] + p1[(size_t)q1 * 256 + c]) * wb;
  ((f32x4*)out)[i] = r;
}

// ---------- launch ----------
extern "C" void kernel_launch(void* const* d_in, const int* in_sizes, int n_in,
                              void* d_out, int out_size, void* d_ws, size_t ws_size,
                              hipStream_t stream) {
  (void)in_sizes; (void)n_in; (void)out_size; (void)ws_size;
  const float* hidden = (const float*)d_in[0];
  const int*   eidx   = (const int*)d_in[1];
  const float* ew     = (const float*)d_in[2];
  const float* rlog   = (const float*)d_in[3];
  const float* w1     = (const float*)d_in[4];
  const float* b1     = (const float*)d_in[5];
  const float* w2     = (const float*)d_in[6];
  const float* b2     = (const float*)d_in[7];
  float* out = (float*)d_out;

  char* wsb = (char*)d_ws;
  const size_t SZ_W = (size_t)ENUM * DDIM * FDIM * 2;  // 64 MiB (bf16)
  unsigned short* w1T = (unsigned short*)(wsb);
  unsigned short* w2T = (unsigned short*)(wsb + SZ_W);
  unsigned short* hB  = (unsigned short*)(wsb + 2 * SZ_W);
  unsigned short* h1  = (unsigned short*)(wsb + 2 * SZ_W + (size_t)TTOK * DDIM * 2);
  int* g_cnt   = (int*)(wsb + 2 * SZ_W + (size_t)TTOK * DDIM * 2 + (size_t)PPAIR * FDIM * 2);
  int* g_off   = g_cnt + 8;
  int* pairTok = g_off + 8;
  int* inv     = pairTok + PPAIR;
  int* b256E   = inv + PPAIR;
  int* b256M   = b256E + 32;
  int* b128E   = b256M + 32;
  int* b128M   = b128E + 16;
  int* nT      = b128M + 16;
  float* pstats = (float*)(nT + 2);
  // h2p (2 x 8192 x 1024 fp32 = 64 MiB) aliases w1T exactly (dead after gemm1)
  float* h2p = (float*)wsb;

  pre_kernel<<<2065 + 8192, 256, 0, stream>>>(hidden, hB, rlog, pstats, eidx, g_cnt, g_off,
                                              pairTok, inv, b256E, b256M, b128E, b128M, nT,
                                              w1, w1T);
  statsB_kernel<<<1, 64, 0, stream>>>(pstats, out);
  gemm1_fused<<<dim3(48, 16 + 171), 512, 0, stream>>>(hB, w1T, b1, g_cnt, g_off, pairTok,
                                                      b256E, b256M, b128E, b128M, nT, h1,
                                                      w2, w2T);
  gemm2_fused<<<dim3(48, 4, 2), 512, 0, stream>>>(h1, w2T, b2, g_cnt, g_off,
                                                  b256E, b256M, b128E, b128M, nT, h2p);
  combine_kernel<<<(TTOK * DDIM / 4) / 256, 256, 0, stream>>>(h2p, ew, inv, out);
}